// Round 3
// baseline (564.620 us; speedup 1.0000x reference)
//
#include <hip/hip_runtime.h>
#include <hip/hip_bf16.h>
#include <stdint.h>

// Problem dims: R=64 cells, C=2048 genes, E=128, H=8 heads, HD=16, D=R*HD=1024
typedef unsigned short u16;
typedef __attribute__((ext_vector_type(8))) short s16x8;
typedef __attribute__((ext_vector_type(4))) float f32x4;

__device__ __forceinline__ u16 f2bf(float f) {
    union { float f; uint32_t u; } v; v.f = f;
    uint32_t r = v.u + 0x7fffu + ((v.u >> 16) & 1u);
    return (u16)(r >> 16);
}
__device__ __forceinline__ float bf2f(u16 b) {
    union { uint32_t u; float f; } v; v.u = ((uint32_t)b) << 16;
    return v.f;
}
__device__ __forceinline__ void split2(float f, u16& h, u16& l) {
    h = f2bf(f);
    l = f2bf(f - bf2f(h));
}

__device__ __forceinline__ void load_lds16(const void* g, void* l) {
    __builtin_amdgcn_global_load_lds(
        (const __attribute__((address_space(1))) unsigned int*)g,
        (__attribute__((address_space(3))) unsigned int*)l,
        16, 0, 0);
}

// ---------------------------------------------------------------------------
// P1: projections, split-bf16 (hi/lo) MFMA for near-fp32 accuracy.
// Block = 128 consecutive (r,c) flat rows (fixed r), 256 threads, 2 blocks/CU.
// X staged hi/lo in LDS (66 KiB); W fragments loaded directly from global
// (L2-hot, 192 KiB total) and split in registers.
//  q: softmax over each 16-group (head_dim) + *1/32, write Qs (h,c,d) bf16
//  k: write KTf (h,d,c) fp32 logits (softmax needs fp32 inputs)
//  v: write VT (h,d,c) bf16
// ---------------------------------------------------------------------------
__global__ __launch_bounds__(256, 2)
void proj_kernel(const float* __restrict__ x,
                 const float* __restrict__ Wq, const float* __restrict__ bq,
                 const float* __restrict__ Wk, const float* __restrict__ bk,
                 const float* __restrict__ Wv, const float* __restrict__ bv,
                 u16* __restrict__ Qs, float* __restrict__ KTf, u16* __restrict__ VT)
{
    // stride 132 u16 (264 B rows): b128 reads step 2 banks/row -> ~2-way max
    __shared__ u16 Xh[128 * 132], Xl[128 * 132];
    const int tid = threadIdx.x;
    const int i0 = blockIdx.x * 128;       // flat row = r*2048 + c
    const int r  = i0 >> 11;
    const int c0 = i0 & 2047;

    {   // stage X tile (128x128 fp32 -> bf16 hi+lo in LDS)
        const int col = (tid & 31) * 4;
        const int rb  = tid >> 5;
        #pragma unroll
        for (int pp = 0; pp < 16; ++pp) {
            int row = pp * 8 + rb;
            float4 v = *(const float4*)(x + (size_t)(i0 + row) * 128 + col);
            ushort4 hi, lo;
            split2(v.x, hi.x, lo.x); split2(v.y, hi.y, lo.y);
            split2(v.z, hi.z, lo.z); split2(v.w, hi.w, lo.w);
            *(ushort4*)&Xh[row * 132 + col] = hi;
            *(ushort4*)&Xl[row * 132 + col] = lo;
        }
    }
    __syncthreads();   // X read-only from here on; no further barriers needed

    const int lane = tid & 63;
    const int w = tid >> 6;
    const int wr = w >> 1, wc = w & 1;
    const int lr = lane & 15, kc = lane >> 4;
    const f32x4 fzero = {0.f, 0.f, 0.f, 0.f};

    const float* const Wp[3] = { Wq, Wk, Wv };
    const float* const bp[3] = { bq, bk, bv };

    #pragma unroll
    for (int p = 0; p < 3; ++p) {
        const float* W = Wp[p];

        f32x4 acc[4][4];
        #pragma unroll
        for (int m = 0; m < 4; ++m)
            #pragma unroll
            for (int n = 0; n < 4; ++n) acc[m][n] = fzero;

        #pragma unroll
        for (int k0 = 0; k0 < 128; k0 += 32) {
            s16x8 ah[4], al[4];
            #pragma unroll
            for (int m = 0; m < 4; ++m) {
                ah[m] = *(const s16x8*)&Xh[(wr*64 + m*16 + lr) * 132 + k0 + kc*8];
                al[m] = *(const s16x8*)&Xl[(wr*64 + m*16 + lr) * 132 + k0 + kc*8];
            }
            #pragma unroll
            for (int n = 0; n < 4; ++n) {
                const float* wp8 = W + (size_t)(wc*64 + n*16 + lr) * 128 + k0 + kc*8;
                float4 w0 = *(const float4*)wp8;
                float4 w1 = *(const float4*)(wp8 + 4);
                s16x8 bh, bl;
                {
                    u16 hh, ll;
                    split2(w0.x, hh, ll); bh[0] = (short)hh; bl[0] = (short)ll;
                    split2(w0.y, hh, ll); bh[1] = (short)hh; bl[1] = (short)ll;
                    split2(w0.z, hh, ll); bh[2] = (short)hh; bl[2] = (short)ll;
                    split2(w0.w, hh, ll); bh[3] = (short)hh; bl[3] = (short)ll;
                    split2(w1.x, hh, ll); bh[4] = (short)hh; bl[4] = (short)ll;
                    split2(w1.y, hh, ll); bh[5] = (short)hh; bl[5] = (short)ll;
                    split2(w1.z, hh, ll); bh[6] = (short)hh; bl[6] = (short)ll;
                    split2(w1.w, hh, ll); bh[7] = (short)hh; bl[7] = (short)ll;
                }
                #pragma unroll
                for (int m = 0; m < 4; ++m) {
                    acc[m][n] = __builtin_amdgcn_mfma_f32_16x16x32_bf16(ah[m], bh, acc[m][n], 0, 0, 0);
                    acc[m][n] = __builtin_amdgcn_mfma_f32_16x16x32_bf16(al[m], bh, acc[m][n], 0, 0, 0);
                    acc[m][n] = __builtin_amdgcn_mfma_f32_16x16x32_bf16(ah[m], bl, acc[m][n], 0, 0, 0);
                }
            }
        }

        float bvals[4];
        #pragma unroll
        for (int n = 0; n < 4; ++n) bvals[n] = bp[p][wc*64 + n*16 + lr];

        // C/D layout: col = lane&15 (= e = h*16+hd, hd=lr), row = kc*4 + j (= c offset)
        if (p == 0) {
            #pragma unroll
            for (int m = 0; m < 4; ++m) {
                #pragma unroll
                for (int n = 0; n < 4; ++n) {
                    const int h  = wc*4 + n;
                    const int cb = c0 + wr*64 + m*16 + kc*4;
                    #pragma unroll
                    for (int j = 0; j < 4; ++j) {
                        float v = acc[m][n][j] + bvals[n];
                        float mx = v;
                        #pragma unroll
                        for (int s = 8; s >= 1; s >>= 1)
                            mx = fmaxf(mx, __shfl_xor(mx, s, 16));
                        float e = __expf(v - mx);
                        float sm = e;
                        #pragma unroll
                        for (int s = 8; s >= 1; s >>= 1)
                            sm += __shfl_xor(sm, s, 16);
                        float o = e / sm * 0.03125f;   // * dim^-0.5 = 1/32
                        Qs[((size_t)h * 2048 + cb + j) * 1024 + r*16 + lr] = f2bf(o);
                    }
                }
            }
        } else if (p == 1) {
            #pragma unroll
            for (int m = 0; m < 4; ++m) {
                #pragma unroll
                for (int n = 0; n < 4; ++n) {
                    const int h  = wc*4 + n;
                    const int cb = c0 + wr*64 + m*16 + kc*4;
                    float4 pk;
                    pk.x = acc[m][n][0] + bvals[n];
                    pk.y = acc[m][n][1] + bvals[n];
                    pk.z = acc[m][n][2] + bvals[n];
                    pk.w = acc[m][n][3] + bvals[n];
                    *(float4*)&KTf[((size_t)(h*1024 + r*16 + lr)) * 2048 + cb] = pk;
                }
            }
        } else {
            #pragma unroll
            for (int m = 0; m < 4; ++m) {
                #pragma unroll
                for (int n = 0; n < 4; ++n) {
                    const int h  = wc*4 + n;
                    const int cb = c0 + wr*64 + m*16 + kc*4;
                    ushort4 pk;
                    pk.x = f2bf(acc[m][n][0] + bvals[n]);
                    pk.y = f2bf(acc[m][n][1] + bvals[n]);
                    pk.z = f2bf(acc[m][n][2] + bvals[n]);
                    pk.w = f2bf(acc[m][n][3] + bvals[n]);
                    *(ushort4*)&VT[((size_t)(h*1024 + r*16 + lr)) * 2048 + cb] = pk;
                }
            }
        }
    }
}

// ---------------------------------------------------------------------------
// S2a: column softmax of k == row softmax of KTf (h,d,c) over c=2048 in fp32.
// Reads fp32 logits, writes bf16 softmaxed values to KTsm (h,d,c).
// ---------------------------------------------------------------------------
__global__ __launch_bounds__(256)
void ksm_kernel(const float* __restrict__ KTf, u16* __restrict__ KTsm)
{
    const float* p = KTf + (size_t)blockIdx.x * 2048;
    u16* o = KTsm + (size_t)blockIdx.x * 2048;
    const int t = threadIdx.x;
    float4 a = *(const float4*)(p + t * 8);
    float4 b = *(const float4*)(p + t * 8 + 4);
    float v[8] = {a.x, a.y, a.z, a.w, b.x, b.y, b.z, b.w};
    float mx = v[0];
    #pragma unroll
    for (int j = 1; j < 8; ++j) mx = fmaxf(mx, v[j]);
    #pragma unroll
    for (int s = 32; s >= 1; s >>= 1) mx = fmaxf(mx, __shfl_xor(mx, s, 64));
    __shared__ float redm[4], reds[4];
    const int w = t >> 6;
    if ((t & 63) == 0) redm[w] = mx;
    __syncthreads();
    mx = fmaxf(fmaxf(redm[0], redm[1]), fmaxf(redm[2], redm[3]));
    float e[8]; float sm = 0.f;
    #pragma unroll
    for (int j = 0; j < 8; ++j) { e[j] = __expf(v[j] - mx); sm += e[j]; }
    #pragma unroll
    for (int s = 32; s >= 1; s >>= 1) sm += __shfl_xor(sm, s, 64);
    if ((t & 63) == 0) reds[w] = sm;
    __syncthreads();
    sm = reds[0] + reds[1] + reds[2] + reds[3];
    const float inv = 1.f / sm;
    uint4 ov; u16* op = (u16*)&ov;
    #pragma unroll
    for (int j = 0; j < 8; ++j) op[j] = f2bf(e[j] * inv);
    *(uint4*)(o + t * 8) = ov;
}

// ---------------------------------------------------------------------------
// S2b: transpose KTsm (h,1024,2048) -> Ksm (h,2048,1024), 64x64 LDS tiles.
// ---------------------------------------------------------------------------
__global__ __launch_bounds__(256)
void ktrans_kernel(const u16* __restrict__ KTsm, u16* __restrict__ Ksm)
{
    const int h  = blockIdx.z;
    const int d0 = blockIdx.y * 64;
    const int c0 = blockIdx.x * 64;
    __shared__ u16 tile[64][72];
    const int t = threadIdx.x;
    #pragma unroll
    for (int i = 0; i < 2; ++i) {
        int g = t + i * 256;
        int dr = g >> 3;
        int cc = (g & 7) * 8;
        uint4 val = *(const uint4*)(KTsm + ((size_t)(h * 1024 + d0 + dr)) * 2048 + c0 + cc);
        *(uint4*)&tile[dr][cc] = val;
    }
    __syncthreads();
    #pragma unroll
    for (int i = 0; i < 2; ++i) {
        int g = t + i * 256;
        int cr = g >> 3;
        int dc = (g & 7) * 8;
        uint4 ov; u16* op = (u16*)&ov;
        #pragma unroll
        for (int j = 0; j < 8; ++j) op[j] = tile[dc + j][cr];
        *(uint4*)(Ksm + ((size_t)(h * 2048 + c0 + cr)) * 1024 + d0 + dc) = ov;
    }
}

// ---------------------------------------------------------------------------
// Batched BT-form GEMM (m97 structure): C[h][i][j] = sum_k A[h][i][k]*B[h][j][k]
// 128x128 tile, BK=32, 4 waves each 64x64, 16x16x32 bf16 MFMA,
// global_load_lds width-16 staging, 2 barriers per K-step.
// MODE 0: fp32 row-major out (attn). MODE 1: bf16 row-major out (CTX^T).
// MODE 2: fp32 scatter to (r,c,h,hd) output layout.
// ---------------------------------------------------------------------------
template<int MODE>
__global__ __launch_bounds__(256, 2)
void gemm_bt(const u16* __restrict__ Aall, const u16* __restrict__ Ball,
             float* __restrict__ outF, u16* __restrict__ outB,
             const int M, const int N, const int K)
{
    const int h  = blockIdx.z;
    const int m0 = blockIdx.y * 128;
    const int n0 = blockIdx.x * 128;
    const u16* A = Aall + (size_t)h * M * K;
    const u16* B = Ball + (size_t)h * N * K;
    __shared__ u16 As[128 * 32];
    __shared__ u16 Bs[128 * 32];
    const int tid = threadIdx.x;
    const int lane = tid & 63;
    const int w = tid >> 6;
    const int wr = w >> 1, wc = w & 1;
    const int lr = lane & 15, kc = lane >> 4;
    const f32x4 fzero = {0.f, 0.f, 0.f, 0.f};

    f32x4 acc[4][4];
    #pragma unroll
    for (int m = 0; m < 4; ++m)
        #pragma unroll
        for (int n = 0; n < 4; ++n) acc[m][n] = fzero;

    const int srow = tid >> 2;          // 0..63
    const int scol = (tid & 3) * 8;     // 0,8,16,24
    const u16* ga = A + (size_t)(m0 + srow) * K + scol;
    const u16* gb = B + (size_t)(n0 + srow) * K + scol;
    char* lA = (char*)As + tid * 16;
    char* lB = (char*)Bs + tid * 16;
    const size_t rstep = (size_t)64 * K;

    for (int k0 = 0; k0 < K; k0 += 32) {
        __syncthreads();                 // prior compute done before overwrite
        load_lds16(ga,         lA);
        load_lds16(ga + rstep, lA + 4096);
        load_lds16(gb,         lB);
        load_lds16(gb + rstep, lB + 4096);
        ga += 32; gb += 32;
        __syncthreads();                 // compiler drains vmcnt before barrier

        s16x8 a[4], b[4];
        #pragma unroll
        for (int m = 0; m < 4; ++m)
            a[m] = *(const s16x8*)((const char*)As + (((wr*64 + m*16 + lr) * 32) + kc*8) * 2);
        #pragma unroll
        for (int n = 0; n < 4; ++n)
            b[n] = *(const s16x8*)((const char*)Bs + (((wc*64 + n*16 + lr) * 32) + kc*8) * 2);
        #pragma unroll
        for (int m = 0; m < 4; ++m)
            #pragma unroll
            for (int n = 0; n < 4; ++n)
                acc[m][n] = __builtin_amdgcn_mfma_f32_16x16x32_bf16(a[m], b[n], acc[m][n], 0, 0, 0);
    }

    #pragma unroll
    for (int m = 0; m < 4; ++m) {
        #pragma unroll
        for (int n = 0; n < 4; ++n) {
            const int grow0 = m0 + wr*64 + m*16 + kc*4;
            const int gcol  = n0 + wc*64 + n*16 + lr;
            #pragma unroll
            for (int j = 0; j < 4; ++j) {
                const float v = acc[m][n][j];
                const int grow = grow0 + j;
                if (MODE == 0) {
                    outF[(size_t)h * M * N + (size_t)grow * N + gcol] = v;
                } else if (MODE == 1) {
                    outB[(size_t)h * M * N + (size_t)grow * N + gcol] = f2bf(v);
                } else {
                    const int rr = gcol >> 4, hd = gcol & 15;   // gcol = e = r*16+hd
                    outF[((size_t)rr * 2048 + grow) * 128 + h * 16 + hd] = v;
                }
            }
        }
    }
}

// ---------------------------------------------------------------------------
// Scratch placement (ws requirement reduced 96 -> 64 MiB):
//   d_ws  [ 0..32M)  Qs   (8,2048,1024) bf16   read by G3, G1 (must persist)
//   d_ws  [32..64M)  Ksm  (8,2048,1024) bf16   read by G1 (must persist)
//   outT  [ 0..32M)  KTsm (8,1024,2048) bf16   dead after G2; G3 overwrites outT
//   attn  [ 0..32M)  VT   (8,1024,2048) bf16   dead after G2
//   attn  [32..48M)  CT   (8,1024,1024) bf16   dead after G3
//   attn  [48..112M) KTf  (8,1024,2048) fp32   dead after ksm
//   G1 (writes attn) runs last; G3 (writes outT) runs after G2.
// ---------------------------------------------------------------------------
extern "C" void kernel_launch(void* const* d_in, const int* in_sizes, int n_in,
                              void* d_out, int out_size, void* d_ws, size_t ws_size,
                              hipStream_t stream)
{
    const float* x  = (const float*)d_in[0];
    const float* Wq = (const float*)d_in[1];
    const float* bq = (const float*)d_in[2];
    const float* Wk = (const float*)d_in[3];
    const float* bk = (const float*)d_in[4];
    const float* Wv = (const float*)d_in[5];
    const float* bv = (const float*)d_in[6];

    float* outT = (float*)d_out;                        // (64,2048,128) fp32, 64 MiB
    float* attn = outT + (size_t)64 * 2048 * 128;       // (8,2048,2048) fp32, 128 MiB

    u16* Qs   = (u16*)d_ws;                              // 32 MiB
    u16* Ksm  = Qs + (size_t)8 * 2048 * 1024;            // 32 MiB
    u16* KTsm = (u16*)outT;                              // 32 MiB (in outT region)
    u16*   VT  = (u16*)attn;                             // 32 MiB @ attn+0
    u16*   CT  = VT + (size_t)8 * 1024 * 2048;           // 16 MiB @ attn+32M
    float* KTf = (float*)(CT + (size_t)8 * 1024 * 1024); // 64 MiB @ attn+48M

    proj_kernel<<<1024, 256, 0, stream>>>(x, Wq, bq, Wk, bk, Wv, bv, Qs, KTf, VT);
    ksm_kernel<<<8192, 256, 0, stream>>>(KTf, KTsm);
    ktrans_kernel<<<dim3(32, 16, 8), 256, 0, stream>>>(KTsm, Ksm);
    // G2: CT[e][d] = sum_n VT[e][n] * KTsm[d][n]   (context^T)
    gemm_bt<1><<<dim3(8, 8, 8),  256, 0, stream>>>(VT, KTsm, nullptr, CT, 1024, 1024, 2048);
    // G3: out[n][e] = sum_d Qs[n][d] * CT[e][d]  -> scatter to (r,c,h,hd); overwrites KTsm
    gemm_bt<2><<<dim3(8, 16, 8), 256, 0, stream>>>(Qs, CT, outT, nullptr, 2048, 1024, 1024);
    // G1: attn[n][m] = sum_d Qs[n][d] * Ksm[m][d]   (last: overwrites VT/CT/KTf scratch)
    gemm_bt<0><<<dim3(16, 16, 8), 256, 0, stream>>>(Qs, Ksm, attn, nullptr, 2048, 2048, 1024);
}

// Round 8
// 542.197 us; speedup vs baseline: 1.0414x; 1.0414x over previous
//
#include <hip/hip_runtime.h>
#include <hip/hip_bf16.h>
#include <stdint.h>

// Problem dims: R=64 cells, C=2048 genes, E=128, H=8 heads, HD=16, D=R*HD=1024
typedef unsigned short u16;
typedef __attribute__((ext_vector_type(8))) short s16x8;
typedef __attribute__((ext_vector_type(4))) float f32x4;

__device__ __forceinline__ u16 f2bf(float f) {
    union { float f; uint32_t u; } v; v.f = f;
    uint32_t r = v.u + 0x7fffu + ((v.u >> 16) & 1u);
    return (u16)(r >> 16);
}
__device__ __forceinline__ float bf2f(u16 b) {
    union { uint32_t u; float f; } v; v.u = ((uint32_t)b) << 16;
    return v.f;
}
__device__ __forceinline__ void split2(float f, u16& h, u16& l) {
    h = f2bf(f);
    l = f2bf(f - bf2f(h));
}

__device__ __forceinline__ void load_lds16(const void* g, void* l) {
    __builtin_amdgcn_global_load_lds(
        (const __attribute__((address_space(1))) unsigned int*)g,
        (__attribute__((address_space(3))) unsigned int*)l,
        16, 0, 0);
}

// ---------------------------------------------------------------------------
// P0: one-time hi/lo bf16 split of Wq/Wk/Wv into Wsp (192 KB, L2-hot after).
// Layout: Wsp[p*32768 + 0..16383] = hi(W_p), Wsp[p*32768 + 16384..] = lo(W_p).
// ---------------------------------------------------------------------------
__global__ __launch_bounds__(256)
void wsplit_kernel(const float* __restrict__ Wq, const float* __restrict__ Wk,
                   const float* __restrict__ Wv, u16* __restrict__ Wsp)
{
    const int i = blockIdx.x * 256 + threadIdx.x;   // 0..49151
    const int p = i >> 14;
    const int j = i & 16383;
    const float* W = (p == 0) ? Wq : (p == 1) ? Wk : Wv;
    const float v = W[j];
    u16 h, l; split2(v, h, l);
    Wsp[(size_t)p * 32768 + j]         = h;
    Wsp[(size_t)p * 32768 + 16384 + j] = l;
}

// ---------------------------------------------------------------------------
// P1: projections, split-bf16 (hi/lo) MFMA for near-fp32 accuracy.
// Block = 64 consecutive (r,c) flat rows (fixed r), 256 threads = 4 waves,
// LDS 33 KB -> 4 blocks/CU (16 waves/CU, ~50% occupancy).
// X staged hi/lo in LDS; W fragments loaded pre-split from Wsp (bf16, L2-hot).
//  q: softmax over each 16-group (head_dim) + *1/32, write Qs (h,c,d) bf16
//  k: write KTf (h,d,c) fp32 logits (softmax needs fp32 inputs)
//  v: write VT (h,d,c) bf16
// ---------------------------------------------------------------------------
__global__ __launch_bounds__(256, 4)
void proj_kernel(const float* __restrict__ x, const u16* __restrict__ Wsp,
                 const float* __restrict__ bq, const float* __restrict__ bk,
                 const float* __restrict__ bv,
                 u16* __restrict__ Qs, float* __restrict__ KTf, u16* __restrict__ VT)
{
    // stride 132 u16 (264 B rows): b128 reads step 2 banks/row -> ~2-way max
    __shared__ u16 Xh[64 * 132], Xl[64 * 132];
    const int tid = threadIdx.x;
    const int i0 = blockIdx.x * 64;        // flat row = r*2048 + c
    const int r  = i0 >> 11;
    const int c0 = i0 & 2047;

    {   // stage X tile (64x128 fp32 -> bf16 hi+lo in LDS)
        const int col = (tid & 31) * 4;
        const int rb  = tid >> 5;
        #pragma unroll
        for (int pp = 0; pp < 8; ++pp) {
            int row = pp * 8 + rb;
            float4 v = *(const float4*)(x + (size_t)(i0 + row) * 128 + col);
            ushort4 hi, lo;
            split2(v.x, hi.x, lo.x); split2(v.y, hi.y, lo.y);
            split2(v.z, hi.z, lo.z); split2(v.w, hi.w, lo.w);
            *(ushort4*)&Xh[row * 132 + col] = hi;
            *(ushort4*)&Xl[row * 132 + col] = lo;
        }
    }
    __syncthreads();   // X read-only from here on

    const int lane = tid & 63;
    const int w = tid >> 6;
    const int wr = w >> 1, wc = w & 1;      // wave tile: rows wr*32+32, cols wc*64+64
    const int lr = lane & 15, kc = lane >> 4;
    const f32x4 fzero = {0.f, 0.f, 0.f, 0.f};

    const float* const bp[3] = { bq, bk, bv };

    #pragma unroll
    for (int p = 0; p < 3; ++p) {
        const u16* Wh = Wsp + (size_t)p * 32768;   // [128 e][128 k] bf16 hi; +16384 = lo

        f32x4 acc[2][4];
        #pragma unroll
        for (int m = 0; m < 2; ++m)
            #pragma unroll
            for (int n = 0; n < 4; ++n) acc[m][n] = fzero;

        #pragma unroll
        for (int k0 = 0; k0 < 128; k0 += 32) {
            s16x8 ah[2], al[2];
            #pragma unroll
            for (int m = 0; m < 2; ++m) {
                ah[m] = *(const s16x8*)&Xh[(wr*32 + m*16 + lr) * 132 + k0 + kc*8];
                al[m] = *(const s16x8*)&Xl[(wr*32 + m*16 + lr) * 132 + k0 + kc*8];
            }
            #pragma unroll
            for (int n = 0; n < 4; ++n) {
                const u16* wb = Wh + (wc*64 + n*16 + lr) * 128 + k0 + kc*8;
                s16x8 bh = *(const s16x8*)wb;
                s16x8 bl = *(const s16x8*)(wb + 16384);
                #pragma unroll
                for (int m = 0; m < 2; ++m) {
                    acc[m][n] = __builtin_amdgcn_mfma_f32_16x16x32_bf16(ah[m], bh, acc[m][n], 0, 0, 0);
                    acc[m][n] = __builtin_amdgcn_mfma_f32_16x16x32_bf16(al[m], bh, acc[m][n], 0, 0, 0);
                    acc[m][n] = __builtin_amdgcn_mfma_f32_16x16x32_bf16(ah[m], bl, acc[m][n], 0, 0, 0);
                }
            }
        }

        float bvals[4];
        #pragma unroll
        for (int n = 0; n < 4; ++n) bvals[n] = bp[p][wc*64 + n*16 + lr];

        // C/D layout: col = lane&15 (= e = h*16+hd, hd=lr), row = kc*4 + j (= c offset)
        if (p == 0) {
            #pragma unroll
            for (int m = 0; m < 2; ++m) {
                #pragma unroll
                for (int n = 0; n < 4; ++n) {
                    const int h  = wc*4 + n;
                    const int cb = c0 + wr*32 + m*16 + kc*4;
                    #pragma unroll
                    for (int j = 0; j < 4; ++j) {
                        float v = acc[m][n][j] + bvals[n];
                        float mx = v;
                        #pragma unroll
                        for (int s = 8; s >= 1; s >>= 1)
                            mx = fmaxf(mx, __shfl_xor(mx, s, 16));
                        float e = __expf(v - mx);
                        float sm = e;
                        #pragma unroll
                        for (int s = 8; s >= 1; s >>= 1)
                            sm += __shfl_xor(sm, s, 16);
                        float o = e / sm * 0.03125f;   // * dim^-0.5 = 1/32
                        Qs[((size_t)h * 2048 + cb + j) * 1024 + r*16 + lr] = f2bf(o);
                    }
                }
            }
        } else if (p == 1) {
            #pragma unroll
            for (int m = 0; m < 2; ++m) {
                #pragma unroll
                for (int n = 0; n < 4; ++n) {
                    const int h  = wc*4 + n;
                    const int cb = c0 + wr*32 + m*16 + kc*4;
                    float4 pk;
                    pk.x = acc[m][n][0] + bvals[n];
                    pk.y = acc[m][n][1] + bvals[n];
                    pk.z = acc[m][n][2] + bvals[n];
                    pk.w = acc[m][n][3] + bvals[n];
                    *(float4*)&KTf[((size_t)(h*1024 + r*16 + lr)) * 2048 + cb] = pk;
                }
            }
        } else {
            #pragma unroll
            for (int m = 0; m < 2; ++m) {
                #pragma unroll
                for (int n = 0; n < 4; ++n) {
                    const int h  = wc*4 + n;
                    const int cb = c0 + wr*32 + m*16 + kc*4;
                    ushort4 pk;
                    pk.x = f2bf(acc[m][n][0] + bvals[n]);
                    pk.y = f2bf(acc[m][n][1] + bvals[n]);
                    pk.z = f2bf(acc[m][n][2] + bvals[n]);
                    pk.w = f2bf(acc[m][n][3] + bvals[n]);
                    *(ushort4*)&VT[((size_t)(h*1024 + r*16 + lr)) * 2048 + cb] = pk;
                }
            }
        }
    }
}

// ---------------------------------------------------------------------------
// S2a: column softmax of k == row softmax of KTf (h,d,c) over c=2048 in fp32.
// Reads fp32 logits, writes bf16 softmaxed values to KTsm (h,d,c).
// ---------------------------------------------------------------------------
__global__ __launch_bounds__(256)
void ksm_kernel(const float* __restrict__ KTf, u16* __restrict__ KTsm)
{
    const float* p = KTf + (size_t)blockIdx.x * 2048;
    u16* o = KTsm + (size_t)blockIdx.x * 2048;
    const int t = threadIdx.x;
    float4 a = *(const float4*)(p + t * 8);
    float4 b = *(const float4*)(p + t * 8 + 4);
    float v[8] = {a.x, a.y, a.z, a.w, b.x, b.y, b.z, b.w};
    float mx = v[0];
    #pragma unroll
    for (int j = 1; j < 8; ++j) mx = fmaxf(mx, v[j]);
    #pragma unroll
    for (int s = 32; s >= 1; s >>= 1) mx = fmaxf(mx, __shfl_xor(mx, s, 64));
    __shared__ float redm[4], reds[4];
    const int w = t >> 6;
    if ((t & 63) == 0) redm[w] = mx;
    __syncthreads();
    mx = fmaxf(fmaxf(redm[0], redm[1]), fmaxf(redm[2], redm[3]));
    float e[8]; float sm = 0.f;
    #pragma unroll
    for (int j = 0; j < 8; ++j) { e[j] = __expf(v[j] - mx); sm += e[j]; }
    #pragma unroll
    for (int s = 32; s >= 1; s >>= 1) sm += __shfl_xor(sm, s, 64);
    if ((t & 63) == 0) reds[w] = sm;
    __syncthreads();
    sm = reds[0] + reds[1] + reds[2] + reds[3];
    const float inv = 1.f / sm;
    uint4 ov; u16* op = (u16*)&ov;
    #pragma unroll
    for (int j = 0; j < 8; ++j) op[j] = f2bf(e[j] * inv);
    *(uint4*)(o + t * 8) = ov;
}

// ---------------------------------------------------------------------------
// S2b: transpose KTsm (h,1024,2048) -> Ksm (h,2048,1024), 64x64 LDS tiles.
// ---------------------------------------------------------------------------
__global__ __launch_bounds__(256)
void ktrans_kernel(const u16* __restrict__ KTsm, u16* __restrict__ Ksm)
{
    const int h  = blockIdx.z;
    const int d0 = blockIdx.y * 64;
    const int c0 = blockIdx.x * 64;
    __shared__ u16 tile[64][72];
    const int t = threadIdx.x;
    #pragma unroll
    for (int i = 0; i < 2; ++i) {
        int g = t + i * 256;
        int dr = g >> 3;
        int cc = (g & 7) * 8;
        uint4 val = *(const uint4*)(KTsm + ((size_t)(h * 1024 + d0 + dr)) * 2048 + c0 + cc);
        *(uint4*)&tile[dr][cc] = val;
    }
    __syncthreads();
    #pragma unroll
    for (int i = 0; i < 2; ++i) {
        int g = t + i * 256;
        int cr = g >> 3;
        int dc = (g & 7) * 8;
        uint4 ov; u16* op = (u16*)&ov;
        #pragma unroll
        for (int j = 0; j < 8; ++j) op[j] = tile[dc + j][cr];
        *(uint4*)(Ksm + ((size_t)(h * 2048 + c0 + cr)) * 1024 + d0 + dc) = ov;
    }
}

// ---------------------------------------------------------------------------
// Batched BT-form GEMM (m97 structure, BK=64): C[h][i][j] = sum_k A[h][i][k]*B[h][j][k]
// 128x128 tile, BK=64 (half the barrier drains of BK=32; 32 MFMAs per step),
// 4 waves each 64x64, 16x16x32 bf16 MFMA, global_load_lds width-16 staging,
// 2 barriers per K-step. LDS 32 KB.
// T1: head-chunked XCD swizzle — grid.z == 8 == NXCD and total%8==0, so the
// remap flat -> (flat&7)*perh + (flat>>3) gives each XCD exactly one head's
// blocks (A/B panels stay resident in that XCD's private L2).
// MODE 0: fp32 row-major out, nontemporal (attn, never re-read).
// MODE 1: bf16 row-major out, cached (CT: re-read by G3 on the same XCD).
// MODE 2: fp32 scatter to (r,c,h,hd) output layout, nontemporal.
// ---------------------------------------------------------------------------
template<int MODE>
__global__ __launch_bounds__(256, 2)
void gemm_bt(const u16* __restrict__ Aall, const u16* __restrict__ Ball,
             float* __restrict__ outF, u16* __restrict__ outB,
             const int M, const int N, const int K)
{
    const int gx = gridDim.x, gy = gridDim.y;
    const int perh = gx * gy;
    int flat = blockIdx.x + gx * (blockIdx.y + gy * blockIdx.z);
    flat = (flat & 7) * perh + (flat >> 3);     // chunk = total/8 = perh (gz==8)
    const int h   = flat / perh;
    const int rem = flat - h * perh;
    const int m0  = (rem / gx) * 128;
    const int n0  = (rem % gx) * 128;
    const u16* A = Aall + (size_t)h * M * K;
    const u16* B = Ball + (size_t)h * N * K;
    __shared__ u16 As[128 * 64];
    __shared__ u16 Bs[128 * 64];
    const int tid = threadIdx.x;
    const int lane = tid & 63;
    const int w = tid >> 6;
    const int wr = w >> 1, wc = w & 1;
    const int lr = lane & 15, kc = lane >> 4;
    const f32x4 fzero = {0.f, 0.f, 0.f, 0.f};

    f32x4 acc[4][4];
    #pragma unroll
    for (int m = 0; m < 4; ++m)
        #pragma unroll
        for (int n = 0; n < 4; ++n) acc[m][n] = fzero;

    const int srow = tid >> 3;          // 0..31
    const int scol = (tid & 7) * 8;     // 0..56 (u16 units)
    const u16* ga = A + (size_t)(m0 + srow) * K + scol;
    const u16* gb = B + (size_t)(n0 + srow) * K + scol;
    char* lA = (char*)As + tid * 16;
    char* lB = (char*)Bs + tid * 16;
    const size_t rstep = (size_t)32 * K;

    for (int k0 = 0; k0 < K; k0 += 64) {
        __syncthreads();                 // prior compute done before overwrite
        load_lds16(ga,             lA);
        load_lds16(ga +     rstep, lA + 4096);
        load_lds16(ga + 2 * rstep, lA + 8192);
        load_lds16(ga + 3 * rstep, lA + 12288);
        load_lds16(gb,             lB);
        load_lds16(gb +     rstep, lB + 4096);
        load_lds16(gb + 2 * rstep, lB + 8192);
        load_lds16(gb + 3 * rstep, lB + 12288);
        ga += 64; gb += 64;
        __syncthreads();                 // compiler drains vmcnt before barrier

        #pragma unroll
        for (int kk = 0; kk < 64; kk += 32) {
            s16x8 a[4], b[4];
            #pragma unroll
            for (int m = 0; m < 4; ++m)
                a[m] = *(const s16x8*)((const char*)As + (((wr*64 + m*16 + lr) * 64) + kk + kc*8) * 2);
            #pragma unroll
            for (int n = 0; n < 4; ++n)
                b[n] = *(const s16x8*)((const char*)Bs + (((wc*64 + n*16 + lr) * 64) + kk + kc*8) * 2);
            #pragma unroll
            for (int m = 0; m < 4; ++m)
                #pragma unroll
                for (int n = 0; n < 4; ++n)
                    acc[m][n] = __builtin_amdgcn_mfma_f32_16x16x32_bf16(a[m], b[n], acc[m][n], 0, 0, 0);
        }
    }

    #pragma unroll
    for (int m = 0; m < 4; ++m) {
        #pragma unroll
        for (int n = 0; n < 4; ++n) {
            const int grow0 = m0 + wr*64 + m*16 + kc*4;
            const int gcol  = n0 + wc*64 + n*16 + lr;
            #pragma unroll
            for (int j = 0; j < 4; ++j) {
                const float v = acc[m][n][j];
                const int grow = grow0 + j;
                if (MODE == 0) {
                    __builtin_nontemporal_store(v, &outF[(size_t)h * M * N + (size_t)grow * N + gcol]);
                } else if (MODE == 1) {
                    outB[(size_t)h * M * N + (size_t)grow * N + gcol] = f2bf(v);
                } else {
                    const int rr = gcol >> 4, hd = gcol & 15;   // gcol = e = r*16+hd
                    __builtin_nontemporal_store(v, &outF[((size_t)rr * 2048 + grow) * 128 + h * 16 + hd]);
                }
            }
        }
    }
}

// ---------------------------------------------------------------------------
// Scratch placement (ws requirement: 64 MiB):
//   d_ws  [ 0..32M)   Qs   (8,2048,1024) bf16   read by G3, G1 (must persist)
//   d_ws  [32..64M)   Ksm  (8,2048,1024) bf16   read by G1 (must persist)
//   outT  [ 0..32M)   KTsm (8,1024,2048) bf16   dead after G2; G3 overwrites outT
//   attn  [ 0..32M)   VT   (8,1024,2048) bf16   dead after G2
//   attn  [32..48M)   CT   (8,1024,1024) bf16   dead after G3
//   attn  [48..112M)  KTf  (8,1024,2048) fp32   dead after ksm
//   attn  [112M..+192K) Wsp hi/lo bf16          dead after proj
//   G1 (writes attn) runs last; G3 (writes outT) runs after G2.
// ---------------------------------------------------------------------------
extern "C" void kernel_launch(void* const* d_in, const int* in_sizes, int n_in,
                              void* d_out, int out_size, void* d_ws, size_t ws_size,
                              hipStream_t stream)
{
    const float* x  = (const float*)d_in[0];
    const float* Wq = (const float*)d_in[1];
    const float* bq = (const float*)d_in[2];
    const float* Wk = (const float*)d_in[3];
    const float* bk = (const float*)d_in[4];
    const float* Wv = (const float*)d_in[5];
    const float* bv = (const float*)d_in[6];

    float* outT = (float*)d_out;                        // (64,2048,128) fp32, 64 MiB
    float* attn = outT + (size_t)64 * 2048 * 128;       // (8,2048,2048) fp32, 128 MiB

    u16* Qs   = (u16*)d_ws;                              // 32 MiB
    u16* Ksm  = Qs + (size_t)8 * 2048 * 1024;            // 32 MiB
    u16* KTsm = (u16*)outT;                              // 32 MiB (in outT region)
    u16*   VT  = (u16*)attn;                             // 32 MiB @ attn+0
    u16*   CT  = VT + (size_t)8 * 1024 * 2048;           // 16 MiB @ attn+32M
    float* KTf = (float*)(CT + (size_t)8 * 1024 * 1024); // 64 MiB @ attn+48M
    u16*   Wsp = (u16*)(KTf + (size_t)8 * 1024 * 2048);  // 192 KiB @ attn+112M

    wsplit_kernel<<<192, 256, 0, stream>>>(Wq, Wk, Wv, Wsp);
    proj_kernel<<<2048, 256, 0, stream>>>(x, Wsp, bq, bk, bv, Qs, KTf, VT);
    ksm_kernel<<<8192, 256, 0, stream>>>(KTf, KTsm);
    ktrans_kernel<<<dim3(32, 16, 8), 256, 0, stream>>>(KTsm, Ksm);
    // G2: CT[e][d] = sum_n VT[e][n] * KTsm[d][n]   (context^T)
    gemm_bt<1><<<dim3(8, 8, 8),  256, 0, stream>>>(VT, KTsm, nullptr, CT, 1024, 1024, 2048);
    // G3: out[n][e] = sum_d Qs[n][d] * CT[e][d]  -> scatter to (r,c,h,hd); overwrites KTsm
    gemm_bt<2><<<dim3(8, 16, 8), 256, 0, stream>>>(Qs, CT, outT, nullptr, 2048, 1024, 1024);
    // G1: attn[n][m] = sum_d Qs[n][d] * Ksm[m][d]   (last: overwrites VT/CT/KTf/Wsp scratch)
    gemm_bt<0><<<dim3(16, 16, 8), 256, 0, stream>>>(Qs, Ksm, attn, nullptr, 2048, 2048, 1024);
}

// Round 9
// 504.491 us; speedup vs baseline: 1.1192x; 1.0747x over previous
//
#include <hip/hip_runtime.h>
#include <hip/hip_bf16.h>
#include <stdint.h>

// Problem dims: R=64 cells, C=2048 genes, E=128, H=8 heads, HD=16, D=R*HD=1024
typedef unsigned short u16;
typedef __attribute__((ext_vector_type(8))) short s16x8;
typedef __attribute__((ext_vector_type(4))) float f32x4;

__device__ __forceinline__ u16 f2bf(float f) {
    union { float f; uint32_t u; } v; v.f = f;
    uint32_t r = v.u + 0x7fffu + ((v.u >> 16) & 1u);
    return (u16)(r >> 16);
}
__device__ __forceinline__ float bf2f(u16 b) {
    union { uint32_t u; float f; } v; v.u = ((uint32_t)b) << 16;
    return v.f;
}
__device__ __forceinline__ void split2(float f, u16& h, u16& l) {
    h = f2bf(f);
    l = f2bf(f - bf2f(h));
}

__device__ __forceinline__ void load_lds16(const void* g, void* l) {
    __builtin_amdgcn_global_load_lds(
        (const __attribute__((address_space(1))) unsigned int*)g,
        (__attribute__((address_space(3))) unsigned int*)l,
        16, 0, 0);
}

// ---------------------------------------------------------------------------
// P0: one-time hi/lo bf16 split of Wq/Wk/Wv into Wsp, SLICE-MAJOR layout for
// proj's bulk global_load_lds staging:
//   12 slices (p=0..2, s=0..3), each 20480 B = [hi: 128e x 40u16][lo: same];
//   row stride 40 u16 (32 data + 8 pad) -> 16B-aligned b128 reads, ~2-way banks.
// Total 240 KB, L2-hot after first touch.
// ---------------------------------------------------------------------------
__global__ __launch_bounds__(256)
void wsplit_kernel(const float* __restrict__ Wq, const float* __restrict__ Wk,
                   const float* __restrict__ Wv, u16* __restrict__ Wsp)
{
    const int i = blockIdx.x * 256 + threadIdx.x;   // 0..49151
    const int p  = i >> 14;          // weight matrix
    const int r  = i & 16383;
    const int s  = r >> 12;          // k-slice (32 wide)
    const int r2 = r & 4095;
    const int e  = r2 >> 5;          // output row 0..127
    const int kk = r2 & 31;          // k within slice
    const float* W = (p == 0) ? Wq : (p == 1) ? Wk : Wv;
    const float v = W[e * 128 + s * 32 + kk];
    u16 h, l; split2(v, h, l);
    const size_t base = (size_t)(p * 4 + s) * 10240;   // u16 units per slice
    Wsp[base + e * 40 + kk]        = h;
    Wsp[base + 5120 + e * 40 + kk] = l;
}

// ---------------------------------------------------------------------------
// P1: projections, split-bf16 (hi/lo) MFMA for near-fp32 accuracy.
// Block = 64 flat rows (fixed r), 256 threads. X hi/lo staged once in LDS
// (stride 136: aligned b128, 2-way banks). W streamed through a DOUBLE-
// BUFFERED LDS slice pipeline (12 slices of 20480 B): stage slice i+1 via
// 5 async global_load_lds per thread while MFMAing slice i; one barrier per
// slice (T3 minimum-2-phase recipe). LDS 74 KB -> 2 blocks/CU.
//  q: softmax over each 16-group (head_dim) + *1/32, write Qs (h,c,d) bf16
//  k: write KTf (h,d,c) fp32 logits (softmax needs fp32 inputs)
//  v: write VT (h,d,c) bf16
// ---------------------------------------------------------------------------
__global__ __launch_bounds__(256, 2)
void proj_kernel(const float* __restrict__ x, const u16* __restrict__ Wsp,
                 const float* __restrict__ bq, const float* __restrict__ bk,
                 const float* __restrict__ bv,
                 u16* __restrict__ Qs, float* __restrict__ KTf, u16* __restrict__ VT)
{
    __shared__ __align__(16) u16 Xh[64 * 136], Xl[64 * 136];
    __shared__ __align__(16) u16 Wlds[2][10240];
    const int tid = threadIdx.x;
    const int i0 = blockIdx.x * 64;        // flat row = r*2048 + c
    const int r  = i0 >> 11;
    const int c0 = i0 & 2047;

    // issue W slice-0 stage FIRST (hides L2 latency under X staging)
    {
        const char* wsrc = (const char*)Wsp;
        char* wdst = (char*)&Wlds[0][0];
        #pragma unroll
        for (int i = 0; i < 5; ++i)
            load_lds16(wsrc + i * 4096 + tid * 16, wdst + i * 4096 + tid * 16);
    }

    {   // stage X tile (64x128 fp32 -> bf16 hi+lo in LDS)
        const int col = (tid & 31) * 4;
        const int rb  = tid >> 5;
        #pragma unroll
        for (int pp = 0; pp < 8; ++pp) {
            int row = pp * 8 + rb;
            float4 v = *(const float4*)(x + (size_t)(i0 + row) * 128 + col);
            ushort4 hi, lo;
            split2(v.x, hi.x, lo.x); split2(v.y, hi.y, lo.y);
            split2(v.z, hi.z, lo.z); split2(v.w, hi.w, lo.w);
            *(ushort4*)&Xh[row * 136 + col] = hi;
            *(ushort4*)&Xl[row * 136 + col] = lo;
        }
    }
    __syncthreads();   // X staged + W slice 0 resident

    const int lane = tid & 63;
    const int w = tid >> 6;
    const int wr = w >> 1, wc = w & 1;      // wave tile: rows wr*32+32, cols wc*64+64
    const int lr = lane & 15, kc = lane >> 4;
    const f32x4 fzero = {0.f, 0.f, 0.f, 0.f};

    const float* const bp[3] = { bq, bk, bv };

    #pragma unroll
    for (int p = 0; p < 3; ++p) {
        f32x4 acc[2][4];
        #pragma unroll
        for (int m = 0; m < 2; ++m)
            #pragma unroll
            for (int n = 0; n < 4; ++n) acc[m][n] = fzero;

        #pragma unroll
        for (int s = 0; s < 4; ++s) {
            const int idx = p * 4 + s;
            // prefetch next slice into the other buffer (async)
            if (idx < 11) {
                const char* wsrc = (const char*)Wsp + (size_t)(idx + 1) * 20480;
                char* wdst = (char*)&Wlds[(idx + 1) & 1][0];
                #pragma unroll
                for (int i = 0; i < 5; ++i)
                    load_lds16(wsrc + i * 4096 + tid * 16, wdst + i * 4096 + tid * 16);
            }

            // compute current slice (k = s*32 .. s*32+31)
            const u16* wbuf = Wlds[idx & 1];
            s16x8 ah[2], al[2];
            #pragma unroll
            for (int m = 0; m < 2; ++m) {
                ah[m] = *(const s16x8*)&Xh[(wr*32 + m*16 + lr) * 136 + s*32 + kc*8];
                al[m] = *(const s16x8*)&Xl[(wr*32 + m*16 + lr) * 136 + s*32 + kc*8];
            }
            #pragma unroll
            for (int n = 0; n < 4; ++n) {
                const u16* wrow = wbuf + (wc*64 + n*16 + lr) * 40 + kc*8;
                s16x8 bh = *(const s16x8*)wrow;
                s16x8 bl = *(const s16x8*)(wrow + 5120);
                #pragma unroll
                for (int m = 0; m < 2; ++m) {
                    acc[m][n] = __builtin_amdgcn_mfma_f32_16x16x32_bf16(ah[m], bh, acc[m][n], 0, 0, 0);
                    acc[m][n] = __builtin_amdgcn_mfma_f32_16x16x32_bf16(al[m], bh, acc[m][n], 0, 0, 0);
                    acc[m][n] = __builtin_amdgcn_mfma_f32_16x16x32_bf16(ah[m], bl, acc[m][n], 0, 0, 0);
                }
            }
            __syncthreads();   // drains stage (vmcnt) + protects buffer reuse
        }

        float bvals[4];
        #pragma unroll
        for (int n = 0; n < 4; ++n) bvals[n] = bp[p][wc*64 + n*16 + lr];

        // C/D layout: col = lane&15 (= e = h*16+hd, hd=lr), row = kc*4 + j (= c offset)
        if (p == 0) {
            #pragma unroll
            for (int m = 0; m < 2; ++m) {
                #pragma unroll
                for (int n = 0; n < 4; ++n) {
                    const int h  = wc*4 + n;
                    const int cb = c0 + wr*32 + m*16 + kc*4;
                    #pragma unroll
                    for (int j = 0; j < 4; ++j) {
                        float v = acc[m][n][j] + bvals[n];
                        float mx = v;
                        #pragma unroll
                        for (int s = 8; s >= 1; s >>= 1)
                            mx = fmaxf(mx, __shfl_xor(mx, s, 16));
                        float e = __expf(v - mx);
                        float sm = e;
                        #pragma unroll
                        for (int s = 8; s >= 1; s >>= 1)
                            sm += __shfl_xor(sm, s, 16);
                        float o = e / sm * 0.03125f;   // * dim^-0.5 = 1/32
                        Qs[((size_t)h * 2048 + cb + j) * 1024 + r*16 + lr] = f2bf(o);
                    }
                }
            }
        } else if (p == 1) {
            #pragma unroll
            for (int m = 0; m < 2; ++m) {
                #pragma unroll
                for (int n = 0; n < 4; ++n) {
                    const int h  = wc*4 + n;
                    const int cb = c0 + wr*32 + m*16 + kc*4;
                    float4 pk;
                    pk.x = acc[m][n][0] + bvals[n];
                    pk.y = acc[m][n][1] + bvals[n];
                    pk.z = acc[m][n][2] + bvals[n];
                    pk.w = acc[m][n][3] + bvals[n];
                    *(float4*)&KTf[((size_t)(h*1024 + r*16 + lr)) * 2048 + cb] = pk;
                }
            }
        } else {
            #pragma unroll
            for (int m = 0; m < 2; ++m) {
                #pragma unroll
                for (int n = 0; n < 4; ++n) {
                    const int h  = wc*4 + n;
                    const int cb = c0 + wr*32 + m*16 + kc*4;
                    ushort4 pk;
                    pk.x = f2bf(acc[m][n][0] + bvals[n]);
                    pk.y = f2bf(acc[m][n][1] + bvals[n]);
                    pk.z = f2bf(acc[m][n][2] + bvals[n]);
                    pk.w = f2bf(acc[m][n][3] + bvals[n]);
                    *(ushort4*)&VT[((size_t)(h*1024 + r*16 + lr)) * 2048 + cb] = pk;
                }
            }
        }
    }
}

// ---------------------------------------------------------------------------
// S2a: column softmax of k == row softmax of KTf (h,d,c) over c=2048 in fp32.
// Reads fp32 logits, writes bf16 softmaxed values to KTsm (h,d,c).
// ---------------------------------------------------------------------------
__global__ __launch_bounds__(256)
void ksm_kernel(const float* __restrict__ KTf, u16* __restrict__ KTsm)
{
    const float* p = KTf + (size_t)blockIdx.x * 2048;
    u16* o = KTsm + (size_t)blockIdx.x * 2048;
    const int t = threadIdx.x;
    float4 a = *(const float4*)(p + t * 8);
    float4 b = *(const float4*)(p + t * 8 + 4);
    float v[8] = {a.x, a.y, a.z, a.w, b.x, b.y, b.z, b.w};
    float mx = v[0];
    #pragma unroll
    for (int j = 1; j < 8; ++j) mx = fmaxf(mx, v[j]);
    #pragma unroll
    for (int s = 32; s >= 1; s >>= 1) mx = fmaxf(mx, __shfl_xor(mx, s, 64));
    __shared__ float redm[4], reds[4];
    const int w = t >> 6;
    if ((t & 63) == 0) redm[w] = mx;
    __syncthreads();
    mx = fmaxf(fmaxf(redm[0], redm[1]), fmaxf(redm[2], redm[3]));
    float e[8]; float sm = 0.f;
    #pragma unroll
    for (int j = 0; j < 8; ++j) { e[j] = __expf(v[j] - mx); sm += e[j]; }
    #pragma unroll
    for (int s = 32; s >= 1; s >>= 1) sm += __shfl_xor(sm, s, 64);
    if ((t & 63) == 0) reds[w] = sm;
    __syncthreads();
    sm = reds[0] + reds[1] + reds[2] + reds[3];
    const float inv = 1.f / sm;
    uint4 ov; u16* op = (u16*)&ov;
    #pragma unroll
    for (int j = 0; j < 8; ++j) op[j] = f2bf(e[j] * inv);
    *(uint4*)(o + t * 8) = ov;
}

// ---------------------------------------------------------------------------
// S2b: transpose KTsm (h,1024,2048) -> Ksm (h,2048,1024), 64x64 LDS tiles.
// ---------------------------------------------------------------------------
__global__ __launch_bounds__(256)
void ktrans_kernel(const u16* __restrict__ KTsm, u16* __restrict__ Ksm)
{
    const int h  = blockIdx.z;
    const int d0 = blockIdx.y * 64;
    const int c0 = blockIdx.x * 64;
    __shared__ u16 tile[64][72];
    const int t = threadIdx.x;
    #pragma unroll
    for (int i = 0; i < 2; ++i) {
        int g = t + i * 256;
        int dr = g >> 3;
        int cc = (g & 7) * 8;
        uint4 val = *(const uint4*)(KTsm + ((size_t)(h * 1024 + d0 + dr)) * 2048 + c0 + cc);
        *(uint4*)&tile[dr][cc] = val;
    }
    __syncthreads();
    #pragma unroll
    for (int i = 0; i < 2; ++i) {
        int g = t + i * 256;
        int cr = g >> 3;
        int dc = (g & 7) * 8;
        uint4 ov; u16* op = (u16*)&ov;
        #pragma unroll
        for (int j = 0; j < 8; ++j) op[j] = tile[dc + j][cr];
        *(uint4*)(Ksm + ((size_t)(h * 2048 + c0 + cr)) * 1024 + d0 + dc) = ov;
    }
}

// ---------------------------------------------------------------------------
// Batched BT-form GEMM (m97 structure, BK=64): C[h][i][j] = sum_k A[h][i][k]*B[h][j][k]
// 128x128 tile, BK=64 (half the barrier drains of BK=32; 32 MFMAs per step),
// 4 waves each 64x64, 16x16x32 bf16 MFMA, global_load_lds width-16 staging,
// 2 barriers per K-step. LDS 32 KB.
// T1: head-chunked XCD swizzle — grid.z == 8 == NXCD and total%8==0, so the
// remap flat -> (flat&7)*perh + (flat>>3) gives each XCD exactly one head's
// blocks (A/B panels stay resident in that XCD's private L2).
// MODE 0: fp32 row-major out, nontemporal (attn, never re-read).
// MODE 1: bf16 row-major out, cached (CT: re-read by G3 on the same XCD).
// MODE 2: fp32 scatter to (r,c,h,hd) output layout, nontemporal.
// ---------------------------------------------------------------------------
template<int MODE>
__global__ __launch_bounds__(256, 2)
void gemm_bt(const u16* __restrict__ Aall, const u16* __restrict__ Ball,
             float* __restrict__ outF, u16* __restrict__ outB,
             const int M, const int N, const int K)
{
    const int gx = gridDim.x, gy = gridDim.y;
    const int perh = gx * gy;
    int flat = blockIdx.x + gx * (blockIdx.y + gy * blockIdx.z);
    flat = (flat & 7) * perh + (flat >> 3);     // chunk = total/8 = perh (gz==8)
    const int h   = flat / perh;
    const int rem = flat - h * perh;
    const int m0  = (rem / gx) * 128;
    const int n0  = (rem % gx) * 128;
    const u16* A = Aall + (size_t)h * M * K;
    const u16* B = Ball + (size_t)h * N * K;
    __shared__ u16 As[128 * 64];
    __shared__ u16 Bs[128 * 64];
    const int tid = threadIdx.x;
    const int lane = tid & 63;
    const int w = tid >> 6;
    const int wr = w >> 1, wc = w & 1;
    const int lr = lane & 15, kc = lane >> 4;
    const f32x4 fzero = {0.f, 0.f, 0.f, 0.f};

    f32x4 acc[4][4];
    #pragma unroll
    for (int m = 0; m < 4; ++m)
        #pragma unroll
        for (int n = 0; n < 4; ++n) acc[m][n] = fzero;

    const int srow = tid >> 3;          // 0..31
    const int scol = (tid & 7) * 8;     // 0..56 (u16 units)
    const u16* ga = A + (size_t)(m0 + srow) * K + scol;
    const u16* gb = B + (size_t)(n0 + srow) * K + scol;
    char* lA = (char*)As + tid * 16;
    char* lB = (char*)Bs + tid * 16;
    const size_t rstep = (size_t)32 * K;

    for (int k0 = 0; k0 < K; k0 += 64) {
        __syncthreads();                 // prior compute done before overwrite
        load_lds16(ga,             lA);
        load_lds16(ga +     rstep, lA + 4096);
        load_lds16(ga + 2 * rstep, lA + 8192);
        load_lds16(ga + 3 * rstep, lA + 12288);
        load_lds16(gb,             lB);
        load_lds16(gb +     rstep, lB + 4096);
        load_lds16(gb + 2 * rstep, lB + 8192);
        load_lds16(gb + 3 * rstep, lB + 12288);
        ga += 64; gb += 64;
        __syncthreads();                 // compiler drains vmcnt before barrier

        #pragma unroll
        for (int kk = 0; kk < 64; kk += 32) {
            s16x8 a[4], b[4];
            #pragma unroll
            for (int m = 0; m < 4; ++m)
                a[m] = *(const s16x8*)((const char*)As + (((wr*64 + m*16 + lr) * 64) + kk + kc*8) * 2);
            #pragma unroll
            for (int n = 0; n < 4; ++n)
                b[n] = *(const s16x8*)((const char*)Bs + (((wc*64 + n*16 + lr) * 64) + kk + kc*8) * 2);
            #pragma unroll
            for (int m = 0; m < 4; ++m)
                #pragma unroll
                for (int n = 0; n < 4; ++n)
                    acc[m][n] = __builtin_amdgcn_mfma_f32_16x16x32_bf16(a[m], b[n], acc[m][n], 0, 0, 0);
        }
    }

    #pragma unroll
    for (int m = 0; m < 4; ++m) {
        #pragma unroll
        for (int n = 0; n < 4; ++n) {
            const int grow0 = m0 + wr*64 + m*16 + kc*4;
            const int gcol  = n0 + wc*64 + n*16 + lr;
            #pragma unroll
            for (int j = 0; j < 4; ++j) {
                const float v = acc[m][n][j];
                const int grow = grow0 + j;
                if (MODE == 0) {
                    __builtin_nontemporal_store(v, &outF[(size_t)h * M * N + (size_t)grow * N + gcol]);
                } else if (MODE == 1) {
                    outB[(size_t)h * M * N + (size_t)grow * N + gcol] = f2bf(v);
                } else {
                    const int rr = gcol >> 4, hd = gcol & 15;   // gcol = e = r*16+hd
                    __builtin_nontemporal_store(v, &outF[((size_t)rr * 2048 + grow) * 128 + h * 16 + hd]);
                }
            }
        }
    }
}

// ---------------------------------------------------------------------------
// Scratch placement (ws requirement: 64 MiB):
//   d_ws  [ 0..32M)   Qs   (8,2048,1024) bf16   read by G3, G1 (must persist)
//   d_ws  [32..64M)   Ksm  (8,2048,1024) bf16   read by G1 (must persist)
//   outT  [ 0..32M)   KTsm (8,1024,2048) bf16   dead after G2; G3 overwrites outT
//   attn  [ 0..32M)   VT   (8,1024,2048) bf16   dead after G2
//   attn  [32..48M)   CT   (8,1024,1024) bf16   dead after G3
//   attn  [48..112M)  KTf  (8,1024,2048) fp32   dead after ksm
//   attn  [112M..+240K) Wsp slice-major hi/lo   dead after proj
//   G1 (writes attn) runs last; G3 (writes outT) runs after G2.
// ---------------------------------------------------------------------------
extern "C" void kernel_launch(void* const* d_in, const int* in_sizes, int n_in,
                              void* d_out, int out_size, void* d_ws, size_t ws_size,
                              hipStream_t stream)
{
    const float* x  = (const float*)d_in[0];
    const float* Wq = (const float*)d_in[1];
    const float* bq = (const float*)d_in[2];
    const float* Wk = (const float*)d_in[3];
    const float* bk = (const float*)d_in[4];
    const float* Wv = (const float*)d_in[5];
    const float* bv = (const float*)d_in[6];

    float* outT = (float*)d_out;                        // (64,2048,128) fp32, 64 MiB
    float* attn = outT + (size_t)64 * 2048 * 128;       // (8,2048,2048) fp32, 128 MiB

    u16* Qs   = (u16*)d_ws;                              // 32 MiB
    u16* Ksm  = Qs + (size_t)8 * 2048 * 1024;            // 32 MiB
    u16* KTsm = (u16*)outT;                              // 32 MiB (in outT region)
    u16*   VT  = (u16*)attn;                             // 32 MiB @ attn+0
    u16*   CT  = VT + (size_t)8 * 1024 * 2048;           // 16 MiB @ attn+32M
    float* KTf = (float*)(CT + (size_t)8 * 1024 * 1024); // 64 MiB @ attn+48M
    u16*   Wsp = (u16*)(KTf + (size_t)8 * 1024 * 2048);  // 240 KiB @ attn+112M

    wsplit_kernel<<<192, 256, 0, stream>>>(Wq, Wk, Wv, Wsp);
    proj_kernel<<<2048, 256, 0, stream>>>(x, Wsp, bq, bk, bv, Qs, KTf, VT);
    ksm_kernel<<<8192, 256, 0, stream>>>(KTf, KTsm);
    ktrans_kernel<<<dim3(32, 16, 8), 256, 0, stream>>>(KTsm, Ksm);
    // G2: CT[e][d] = sum_n VT[e][n] * KTsm[d][n]   (context^T)
    gemm_bt<1><<<dim3(8, 8, 8),  256, 0, stream>>>(VT, KTsm, nullptr, CT, 1024, 1024, 2048);
    // G3: out[n][e] = sum_d Qs[n][d] * CT[e][d]  -> scatter to (r,c,h,hd); overwrites KTsm
    gemm_bt<2><<<dim3(8, 16, 8), 256, 0, stream>>>(Qs, CT, outT, nullptr, 2048, 1024, 1024);
    // G1: attn[n][m] = sum_d Qs[n][d] * Ksm[m][d]   (last: overwrites VT/CT/KTf/Wsp scratch)
    gemm_bt<0><<<dim3(16, 16, 8), 256, 0, stream>>>(Qs, Ksm, attn, nullptr, 2048, 2048, 1024);
}